// Round 19
// baseline (734.614 us; speedup 1.0000x reference)
//
#include <hip/hip_runtime.h>
#include <stdint.h>

#define T_STEPS 1024
#define BATCH   512
#define INF     64
#define HID     128
#define OUTF    2
#define G       2      // batch rows per block (weight-fetch amortization)

// d_out[0..1023] = z_sum [512][2], d_out[1024] = spikerate.
__global__ void zero_kernel(unsigned int* __restrict__ counter)
{
    *counter = 0u;
}

#define FOR16(M) M(0)M(1)M(2)M(3)M(4)M(5)M(6)M(7)M(8)M(9)M(10)M(11)M(12)M(13)M(14)M(15)
#define BARRIER() asm volatile("s_waitcnt lgkmcnt(0)\n\ts_barrier" ::: "memory")

// grid 256 x 576 threads (9 waves); block = TWO batch rows b0,b0+1. 74KB LDS.
// Rationale (rounds 12-18): the allocator demotes loop-invariant weight loads
// at ANY declared budget (40-128 VGPR across 7 configs; pins satisfied via
// AGPR shuffle) -> each W-thread refetches weights from L1/L2 every step.
// 96KB/block/step at 2 blocks/CU = 192KB/CU-step ~= the 1610cyc/step limiter.
// Fix: G=2 rows/block -> same weight fetch serves 2 rows (2 accumulators per
// thread, independent bit-exact chains); traffic per CU-step halves.
// Roles (wave-aligned), pipeline at step i (round-16 schedule, row-expanded):
//   tid   0..127 (W2a): q(i+2)   rows 0,1 = chain k=0..63  of inp(i+2) -> q_lds
//   tid 128..255 (W2b): pre(i+1) rows 0,1 = chain k=64..127 CONT q(i+1)-> pre_lds
//   tid 256..383 (W1) : inp(i+3) rows 0,1 = x(i+3) @ W_in.T            -> inp_lds
//   tid 384..447 (R0) : row 0, step i: rec scan (in-wave masks) + LIF + ballots
//   tid 448..511 (R1) : row 1, same
//   tid 512..575 (X)  : x prefetch both rows
// Bit-exact semantics (verified absmax==0.0 rounds 8-18):
//   - v,i state + elementwise: float64, np op order, no contraction
//   - inp/pre: f32 seq-k single-accumulator FMA chains per row (K-split passes
//     the exact f32 partial through LDS; row interleave preserves each chain)
//   - rec: f64 sum of f32 weights — exact in any order
__global__ __launch_bounds__(576, 2)
void snn_seq(const float* __restrict__ x,        // [T][B][64]
             const float* __restrict__ W_in,     // [128][64]
             const float* __restrict__ cWi,      // [128][128]
             const float* __restrict__ Wrec,     // [128][128]
             const float* __restrict__ W_out,    // [2][128]
             const float* __restrict__ b_out,    // [2]
             const float* __restrict__ v_th,     // [128]
             const float* __restrict__ v_leak1,  // [1]
             const float* __restrict__ v_reset,  // [128]
             const float* __restrict__ tau_mem,  // [128]
             const float* __restrict__ tau_syn,  // [128]
             float* __restrict__ out,            // [512][2] + [1]
             unsigned int* __restrict__ counter)
{
    #pragma clang fp contract(off)

    extern __shared__ char smem[];
    float* Wrec_T  = (float*)smem;                 // [128][128]: Wrec_T[j][h] = Wrec[h][j]
    float* inp_lds = Wrec_T + HID * HID;           // [4 slot][G][128]
    float* x_lds   = inp_lds + 4 * G * HID;        // [4 slot][G][64]
    float* q_lds   = x_lds + 4 * G * INF;          // [2 slot][G][128]
    float* pre_lds = q_lds + 2 * G * HID;          // [2 slot][G][128]

    const int tid = threadIdx.x;
    const int b0  = blockIdx.x * G;

    // ---- stage Wrec transposed (all threads)
    for (int idx = tid; idx < HID * HID; idx += 576)
        Wrec_T[idx] = Wrec[(idx & (HID - 1)) * HID + (idx >> 7)];

    if (tid < 128) {
        // ============ W2a: q rows 0,1 = chain(inp[0..63]), cWi first half ============
        const int h = tid;
        const float4* cwr = (const float4*)(cWi + h * HID);
        #define DECL_C(q) float4 c##q = cwr[q];
        FOR16(DECL_C)
        #undef DECL_C

        #define S2A(q) { float4 u = ir0[q]; float4 w = ir1[q]; \
            a0 = fmaf(u.x, c##q.x, a0); a0 = fmaf(u.y, c##q.y, a0); \
            a0 = fmaf(u.z, c##q.z, a0); a0 = fmaf(u.w, c##q.w, a0); \
            a1 = fmaf(w.x, c##q.x, a1); a1 = fmaf(w.y, c##q.y, a1); \
            a1 = fmaf(w.z, c##q.z, a1); a1 = fmaf(w.w, c##q.w, a1); }
        #define DO_W2A(t) { \
            const float4* ir0 = (const float4*)(inp_lds + (((t) & 3) * G + 0) * HID); \
            const float4* ir1 = (const float4*)(inp_lds + (((t) & 3) * G + 1) * HID); \
            float a0 = 0.f, a1 = 0.f; FOR16(S2A) \
            q_lds[(((t) & 1) * G + 0) * HID + h] = a0; \
            q_lds[(((t) & 1) * G + 1) * HID + h] = a1; }

        __syncthreads();                       // B0
        BARRIER();                             // B1 (W1 computed inp(0))
        DO_W2A(0)
        BARRIER();                             // B2
        DO_W2A(1)
        BARRIER();                             // B3
        for (int i = 0; i < T_STEPS; i += 2) {
            DO_W2A(i + 2)
            BARRIER();
            DO_W2A(i + 3)
            BARRIER();
        }
        #undef DO_W2A
        #undef S2A
    } else if (tid < 256) {
        // ============ W2b: pre rows 0,1 = chain(q, inp[64..127]), cWi second half ============
        const int h = tid - 128;
        const float4* cwr = (const float4*)(cWi + h * HID) + 16;
        #define DECL_D(q) float4 d##q = cwr[q];
        FOR16(DECL_D)
        #undef DECL_D

        #define S2B(q) { float4 u = ir0[q]; float4 w = ir1[q]; \
            a0 = fmaf(u.x, d##q.x, a0); a0 = fmaf(u.y, d##q.y, a0); \
            a0 = fmaf(u.z, d##q.z, a0); a0 = fmaf(u.w, d##q.w, a0); \
            a1 = fmaf(w.x, d##q.x, a1); a1 = fmaf(w.y, d##q.y, a1); \
            a1 = fmaf(w.z, d##q.z, a1); a1 = fmaf(w.w, d##q.w, a1); }
        #define DO_W2B(t) { \
            const float4* ir0 = (const float4*)(inp_lds + (((t) & 3) * G + 0) * HID) + 16; \
            const float4* ir1 = (const float4*)(inp_lds + (((t) & 3) * G + 1) * HID) + 16; \
            float a0 = q_lds[(((t) & 1) * G + 0) * HID + h]; \
            float a1 = q_lds[(((t) & 1) * G + 1) * HID + h]; \
            FOR16(S2B) \
            pre_lds[(((t) & 1) * G + 0) * HID + h] = a0; \
            pre_lds[(((t) & 1) * G + 1) * HID + h] = a1; }

        __syncthreads();                       // B0
        BARRIER();                             // B1
        BARRIER();                             // B2
        DO_W2B(0)
        BARRIER();                             // B3
        for (int i = 0; i < T_STEPS; i += 2) {
            DO_W2B(i + 1)
            BARRIER();
            DO_W2B(i + 2)
            BARRIER();
        }
        #undef DO_W2B
        #undef S2B
    } else if (tid < 384) {
        // ============ W1: inp rows 0,1 = x @ W_in.T, one output/lane ============
        const int l = tid - 256;
        const float4* wra = (const float4*)(W_in + l * INF);
        #define DECL_A(q) float4 a##q = wra[q];
        FOR16(DECL_A)
        #undef DECL_A

        #define S1(q) { float4 u = xr0[q]; float4 w = xr1[q]; \
            s0 = fmaf(u.x, a##q.x, s0); s0 = fmaf(u.y, a##q.y, s0); \
            s0 = fmaf(u.z, a##q.z, s0); s0 = fmaf(u.w, a##q.w, s0); \
            s1 = fmaf(w.x, a##q.x, s1); s1 = fmaf(w.y, a##q.y, s1); \
            s1 = fmaf(w.z, a##q.z, s1); s1 = fmaf(w.w, a##q.w, s1); }
        #define DO_W1(t) { \
            const float4* xr0 = (const float4*)(x_lds + (((t) & 3) * G + 0) * INF); \
            const float4* xr1 = (const float4*)(x_lds + (((t) & 3) * G + 1) * INF); \
            float s0 = 0.f, s1 = 0.f; FOR16(S1) \
            inp_lds[(((t) & 3) * G + 0) * HID + l] = s0; \
            inp_lds[(((t) & 3) * G + 1) * HID + l] = s1; }

        __syncthreads();                       // B0 (x(0..3) staged by X)
        DO_W1(0)
        BARRIER();                             // B1
        DO_W1(1)
        BARRIER();                             // B2
        DO_W1(2)
        BARRIER();                             // B3
        for (int i = 0; i < T_STEPS; i += 2) {
            DO_W1(i + 3)
            BARRIER();
            DO_W1(i + 4)
            BARRIER();
        }
        #undef DO_W1
        #undef S1
    } else if (tid < 512) {
        // ============ R0/R1: rec scan + LIF, 2 neurons/lane, one row per wave ============
        const int row = (tid >> 6) & 1;        // 384..447 -> 0, 448..511 -> 1
        const int l   = tid & 63;
        const int h0  = 2 * l, h1 = 2 * l + 1;

        const double vth0  = (double)v_th[h0],    vth1  = (double)v_th[h1];
        const double vleak = (double)v_leak1[0];
        const double vrs0  = (double)v_reset[h0], vrs1  = (double)v_reset[h1];
        const double dtm0  = 0.001 * (double)tau_mem[h0];
        const double dtm1  = 0.001 * (double)tau_mem[h1];
        const double dts0  = 0.001 * (double)tau_syn[h0];
        const double dts1  = 0.001 * (double)tau_syn[h1];

        double v0 = 0.0, v1 = 0.0, c0 = 0.0, c1 = 0.0;
        int cnt0 = 0, cnt1 = 0;
        unsigned long long me = 0ull, mo = 0ull;   // z(i-1) even/odd neurons, this row

        __syncthreads();                       // B0
        BARRIER(); BARRIER(); BARRIER();       // B1,B2,B3

        for (int i = 0; i < T_STEPS; ++i) {
            float2 pp = *(const float2*)(pre_lds + ((i & 1) * G + row) * HID + h0);

            double s00 = 0.0, s01 = 0.0, s10 = 0.0, s11 = 0.0;
            {
                unsigned long long A = me, Bm = mo;
                while (A | Bm) {
                    float2 w0 = make_float2(0.f, 0.f), w1 = w0, w2 = w0, w3 = w0,
                           w4 = w0, w5 = w0, w6 = w0, w7 = w0;
                    if (A)  { int j = __builtin_ctzll(A);  A  &= A - 1;  w0 = *(const float2*)(Wrec_T + (2 * j) * HID + h0); }
                    if (A)  { int j = __builtin_ctzll(A);  A  &= A - 1;  w1 = *(const float2*)(Wrec_T + (2 * j) * HID + h0); }
                    if (A)  { int j = __builtin_ctzll(A);  A  &= A - 1;  w2 = *(const float2*)(Wrec_T + (2 * j) * HID + h0); }
                    if (A)  { int j = __builtin_ctzll(A);  A  &= A - 1;  w3 = *(const float2*)(Wrec_T + (2 * j) * HID + h0); }
                    if (Bm) { int j = __builtin_ctzll(Bm); Bm &= Bm - 1; w4 = *(const float2*)(Wrec_T + (2 * j + 1) * HID + h0); }
                    if (Bm) { int j = __builtin_ctzll(Bm); Bm &= Bm - 1; w5 = *(const float2*)(Wrec_T + (2 * j + 1) * HID + h0); }
                    if (Bm) { int j = __builtin_ctzll(Bm); Bm &= Bm - 1; w6 = *(const float2*)(Wrec_T + (2 * j + 1) * HID + h0); }
                    if (Bm) { int j = __builtin_ctzll(Bm); Bm &= Bm - 1; w7 = *(const float2*)(Wrec_T + (2 * j + 1) * HID + h0); }
                    s00 += (double)w0.x; s10 += (double)w0.y;
                    s01 += (double)w1.x; s11 += (double)w1.y;
                    s00 += (double)w2.x; s10 += (double)w2.y;
                    s01 += (double)w3.x; s11 += (double)w3.y;
                    s00 += (double)w4.x; s10 += (double)w4.y;
                    s01 += (double)w5.x; s11 += (double)w5.y;
                    s00 += (double)w6.x; s10 += (double)w6.y;
                    s01 += (double)w7.x; s11 += (double)w7.y;
                }
            }
            double rec0 = s00 + s01;
            double rec1 = s10 + s11;

            double vd0 = v0 + dtm0 * ((vleak - v0) + c0);
            double id0 = c0 - dts0 * c0;
            bool   z0  = (vd0 - vth0) > 0.0;
            v0 = z0 ? vrs0 : vd0;
            c0 = (id0 + (double)pp.x) + rec0;
            cnt0 += z0 ? 1 : 0;

            double vd1 = v1 + dtm1 * ((vleak - v1) + c1);
            double id1 = c1 - dts1 * c1;
            bool   z1  = (vd1 - vth1) > 0.0;
            v1 = z1 ? vrs1 : vd1;
            c1 = (id1 + (double)pp.y) + rec1;
            cnt1 += z1 ? 1 : 0;

            me = __ballot(z0);   // per-wave => per-row
            mo = __ballot(z1);
            BARRIER();
        }

        pre_lds[row * HID + h0] = (float)cnt0;   // park counts (<=1024: exact)
        pre_lds[row * HID + h1] = (float)cnt1;
    } else {
        // ============ X: x prefetch, both rows ============
        const int l = tid - 512;
        float rA0, rA1, rB0, rB1, rC0, rC1;
        x_lds[(0 * G + 0) * INF + l] = x[(size_t)(0 * BATCH + b0 + 0) * INF + l];
        x_lds[(0 * G + 1) * INF + l] = x[(size_t)(0 * BATCH + b0 + 1) * INF + l];
        x_lds[(1 * G + 0) * INF + l] = x[(size_t)(1 * BATCH + b0 + 0) * INF + l];
        x_lds[(1 * G + 1) * INF + l] = x[(size_t)(1 * BATCH + b0 + 1) * INF + l];
        x_lds[(2 * G + 0) * INF + l] = x[(size_t)(2 * BATCH + b0 + 0) * INF + l];
        x_lds[(2 * G + 1) * INF + l] = x[(size_t)(2 * BATCH + b0 + 1) * INF + l];
        x_lds[(3 * G + 0) * INF + l] = x[(size_t)(3 * BATCH + b0 + 0) * INF + l];
        x_lds[(3 * G + 1) * INF + l] = x[(size_t)(3 * BATCH + b0 + 1) * INF + l];
        rC0 = x[(size_t)(4 * BATCH + b0 + 0) * INF + l];
        rC1 = x[(size_t)(4 * BATCH + b0 + 1) * INF + l];
        rA0 = x[(size_t)(5 * BATCH + b0 + 0) * INF + l];
        rA1 = x[(size_t)(5 * BATCH + b0 + 1) * INF + l];
        rB0 = x[(size_t)(6 * BATCH + b0 + 0) * INF + l];
        rB1 = x[(size_t)(6 * BATCH + b0 + 1) * INF + l];

        __syncthreads();                       // B0
        BARRIER();                             // B1
        BARRIER();                             // B2
        x_lds[(0 * G + 0) * INF + l] = rC0;    // P3: x(4) -> slot 0
        x_lds[(0 * G + 1) * INF + l] = rC1;
        BARRIER();                             // B3
        for (int i = 0; i < T_STEPS; i += 2) {
            {   // even: write x(i+5), load x(i+7)
                const int s = (i + 5) & 3;
                x_lds[(s * G + 0) * INF + l] = rA0;
                x_lds[(s * G + 1) * INF + l] = rA1;
                int tn = (i + 7 < T_STEPS) ? i + 7 : T_STEPS - 1;
                rA0 = x[((size_t)tn * BATCH + b0 + 0) * INF + l];
                rA1 = x[((size_t)tn * BATCH + b0 + 1) * INF + l];
            }
            BARRIER();
            {   // odd: write x(i+6), load x(i+8)
                const int s = (i + 6) & 3;
                x_lds[(s * G + 0) * INF + l] = rB0;
                x_lds[(s * G + 1) * INF + l] = rB1;
                int tn = (i + 8 < T_STEPS) ? i + 8 : T_STEPS - 1;
                rB0 = x[((size_t)tn * BATCH + b0 + 0) * INF + l];
                rB1 = x[((size_t)tn * BATCH + b0 + 1) * INF + l];
            }
            BARRIER();
        }
    }

    __syncthreads();

    // ---- epilogue: z_sum rows b0,b0+1 = (sum_t z)@W_out.T + T*b_out ; spike count
    const float* cnt_lds = pre_lds;            // [2 rows][128] parked counts
    if (tid < G * OUTF) {
        int row = tid >> 1, oo = tid & 1;
        double sAcc = 0.0;
        for (int hh = 0; hh < HID; ++hh)
            sAcc += (double)cnt_lds[row * HID + hh] * (double)W_out[oo * HID + hh];
        out[(size_t)(b0 + row) * OUTF + oo] = (float)(sAcc + 1024.0 * (double)b_out[oo]);
    }
    if (tid == 0) {
        unsigned int tot = 0;
        for (int k2 = 0; k2 < G * HID; ++k2) tot += (unsigned int)cnt_lds[k2];
        atomicAdd(counter, tot);
    }
}

__global__ void finalize_kernel(float* __restrict__ out)
{
    unsigned int c = ((const unsigned int*)out)[BATCH * OUTF];
    out[BATCH * OUTF] = (float)c * 0x1p-26f;   // / (1024*512*128), exact pow2
}

extern "C" void kernel_launch(void* const* d_in, const int* in_sizes, int n_in,
                              void* d_out, int out_size, void* d_ws, size_t ws_size,
                              hipStream_t stream) {
    (void)in_sizes; (void)n_in; (void)d_ws; (void)ws_size; (void)out_size;

    const float* x       = (const float*)d_in[0];
    const float* W_in    = (const float*)d_in[1];
    const float* cWi     = (const float*)d_in[2];
    const float* cWr     = (const float*)d_in[3];
    const float* W_out   = (const float*)d_in[4];
    const float* b_out   = (const float*)d_in[5];
    // d_in[6] = alpha (unused in forward)
    const float* v_th    = (const float*)d_in[7];
    const float* v_leak  = (const float*)d_in[8];
    const float* v_reset = (const float*)d_in[9];
    const float* tau_mem = (const float*)d_in[10];
    const float* tau_syn = (const float*)d_in[11];
    float* out = (float*)d_out;
    unsigned int* counter = (unsigned int*)out + BATCH * OUTF;

    zero_kernel<<<1, 1, 0, stream>>>(counter);

    const size_t lds_bytes =
        (size_t)(HID * HID + 4 * G * HID + 4 * G * INF + 2 * G * HID + 2 * G * HID)
        * sizeof(float);
    snn_seq<<<dim3(BATCH / G), dim3(576), lds_bytes, stream>>>(
        x, W_in, cWi, cWr, W_out, b_out, v_th, v_leak, v_reset,
        tau_mem, tau_syn, out, counter);

    finalize_kernel<<<1, 1, 0, stream>>>(out);
}